// Round 13
// baseline (922.845 us; speedup 1.0000x reference)
//
#include <hip/hip_runtime.h>
#include <hip/hip_bf16.h>

#define N_NODES  100000
#define N_EDGES  1600000
#define N_GRAPHS 256
#define F 64
#define NBUCK  782    // ceil(N_NODES/128), bucket = dst >> 7
#define CHUNK  4096   // edges per partition chunk
#define NCHUNK 391    // ceil(1.6M/4096)
#define GB     391    // ceil(N_NODES/256) gemm blocks (256 nodes/block)

// ======== atomic-free CSR build: two-level counting sort ========

// blocks 0..NCHUNK-1: per-chunk histogram; block NCHUNK: graph-boundary search
__global__ __launch_bounds__(1024) void k_hist(const int* __restrict__ dst, int* __restrict__ hist,
                                               const int* __restrict__ batch, int* __restrict__ gstart) {
    if (blockIdx.x == NCHUNK) {
        int g = threadIdx.x;
        if (g > N_GRAPHS) return;
        int lo = 0, hi = N_NODES;
        while (lo < hi) {
            int mid = (lo + hi) >> 1;
            if (batch[mid] < g) lo = mid + 1; else hi = mid;
        }
        gstart[g] = lo;
        return;
    }
    __shared__ int lh[NBUCK];
    int tid = threadIdx.x, chunk = blockIdx.x;
    for (int j = tid; j < NBUCK; j += 1024) lh[j] = 0;
    __syncthreads();
    int e0 = chunk * CHUNK;
#pragma unroll
    for (int i = 0; i < CHUNK / 1024; i++) {
        int e = e0 + i * 1024 + tid;
        if (e < N_EDGES) atomicAdd(&lh[dst[e] >> 7], 1);
    }
    __syncthreads();
    for (int j = tid; j < NBUCK; j += 1024) hist[chunk * NBUCK + j] = lh[j];
}

__global__ __launch_bounds__(512) void k_colscan(int* __restrict__ hist, int* __restrict__ btot) {
    __shared__ int ts[512];
    int b = blockIdx.x, tid = threadIdx.x;
    int v = (tid < NCHUNK) ? hist[tid * NBUCK + b] : 0;
    ts[tid] = v;
    __syncthreads();
    int x = v;
    for (int off = 1; off < 512; off <<= 1) {
        int t = (tid >= off) ? ts[tid - off] : 0;
        __syncthreads();
        x += t; ts[tid] = x;
        __syncthreads();
    }
    if (tid < NCHUNK) hist[tid * NBUCK + b] = x - v;
    if (tid == 511) btot[b] = x;
}

__global__ __launch_bounds__(256) void k_bscan(const int* __restrict__ btot, int* __restrict__ base) {
    __shared__ int ts[256];
    int tid = threadIdx.x;
    int v[4], loc[4], run = 0;
#pragma unroll
    for (int k = 0; k < 4; k++) {
        int c = tid * 4 + k;
        v[k] = (c < NBUCK) ? btot[c] : 0;
        loc[k] = run; run += v[k];
    }
    ts[tid] = run;
    __syncthreads();
    int x = run;
    for (int off = 1; off < 256; off <<= 1) {
        int t = (tid >= off) ? ts[tid - off] : 0;
        __syncthreads();
        x += t; ts[tid] = x;
        __syncthreads();
    }
    int texcl = x - run;
#pragma unroll
    for (int k = 0; k < 4; k++) {
        int c = tid * 4 + k;
        if (c < NBUCK) base[c] = texcl + loc[k];
    }
    if (tid == 255) base[NBUCK] = x;
}

// edge partition (1024 threads, 3.1 KB LDS -> high occupancy)
__global__ __launch_bounds__(1024) void k_partition(const int* __restrict__ src, const int* __restrict__ dst,
                                                    const float* __restrict__ ew,
                                                    const int* __restrict__ hist, const int* __restrict__ base,
                                                    long long* __restrict__ part) {
    __shared__ int cursor[NBUCK];
    int tid = threadIdx.x, chunk = blockIdx.x;
    for (int j = tid; j < NBUCK; j += 1024) cursor[j] = base[j] + hist[chunk * NBUCK + j];
    __syncthreads();
    int e0 = chunk * CHUNK;
#pragma unroll
    for (int i = 0; i < CHUNK / 1024; i++) {
        int e = e0 + i * 1024 + tid;
        if (e < N_EDGES) {
            int d = dst[e];
            int pos = atomicAdd(&cursor[d >> 7], 1);
            unsigned lo = (unsigned)src[e] | ((unsigned)(d & 127) << 17);
            long long rec = (long long)((unsigned long long)lo |
                            ((unsigned long long)__float_as_uint(ew[e]) << 32));
            part[pos] = rec;
        }
    }
}

// per-bucket pass 1: degrees (LDS float atomics) -> dinv_g, counts -> row_off
__global__ __launch_bounds__(512) void k_deg(const long long* __restrict__ part,
                                             const int* __restrict__ base,
                                             float* __restrict__ dinv_g, int* __restrict__ row_off) {
    __shared__ float fdeg[128];
    __shared__ int   cnt[128];
    __shared__ int   sc[128];
    int b = blockIdx.x, tid = threadIdx.x;
    if (tid < 128) { fdeg[tid] = 1.0f; cnt[tid] = 0; }   // 1.0 = self-loop weight
    __syncthreads();
    int e0 = base[b], e1 = base[b + 1];
    for (int k = e0 + tid; k < e1; k += 512) {
        long long rec = part[k];
        int d7 = ((int)rec >> 17) & 127;
        atomicAdd(&fdeg[d7], __uint_as_float((unsigned)(rec >> 32)));
        atomicAdd(&cnt[d7], 1);
    }
    __syncthreads();
    int myc = 0, x = 0;
    if (tid < 128) {
        int node = b * 128 + tid;
        if (node < N_NODES) dinv_g[node] = rsqrtf(fdeg[tid]);
        myc = cnt[tid]; x = myc; sc[tid] = x;
    }
    __syncthreads();
    for (int off = 1; off < 128; off <<= 1) {
        int t = (tid < 128 && tid >= off) ? sc[tid - off] : 0;
        __syncthreads();
        if (tid < 128) { x += t; sc[tid] = x; }
        __syncthreads();
    }
    if (tid < 128) {
        int node = b * 128 + tid;
        if (node < N_NODES) row_off[node] = e0 + (x - myc);
    }
    if (b == 0 && tid == 0) row_off[N_NODES] = N_EDGES;
}

// per-bucket pass 2: scatter esec = (src*128 byte-off, w*dinv[d]*dinv[src])
__global__ __launch_bounds__(512) void k_scat(const long long* __restrict__ part,
                                              const int* __restrict__ base,
                                              const float* __restrict__ dinv_g,
                                              const int* __restrict__ row_off,
                                              int2* __restrict__ esec) {
    __shared__ int   cursor[128];
    __shared__ float sdinv[128];
    int b = blockIdx.x, tid = threadIdx.x;
    if (tid < 128) {
        int node = b * 128 + tid;
        cursor[tid] = row_off[node < N_NODES ? node : N_NODES];
        sdinv[tid]  = dinv_g[node < N_NODES ? node : 0];
    }
    __syncthreads();
    int e0 = base[b], e1 = base[b + 1];
    for (int k = e0 + tid; k < e1; k += 512) {
        long long rec = part[k];
        int lo = (int)rec;
        int d7 = (lo >> 17) & 127;
        int s  = lo & 0x1FFFF;
        float w = __uint_as_float((unsigned)(rec >> 32));
        float coef = (w * sdinv[d7]) * dinv_g[s];
        int pos = atomicAdd(&cursor[d7], 1);
        esec[pos] = make_int2(s << 7, __float_as_int(coef));   // byte off: src*128 (bf16 row)
    }
    if (b == 0 && tid < 32) esec[N_EDGES + tid] = make_int2(0, 0);  // sentinels for agg overrun
}

// ---------------- GEMM1: H = X_f32[N,128] @ W[128,64], bf16 out ----------------
__global__ __launch_bounds__(256) void k_gemm1(const float* __restrict__ X,
                                               const float* __restrict__ W,
                                               __hip_bfloat16* __restrict__ H) {
    constexpr int K = 128;
    constexpr int KC = 32;
    constexpr int XP = KC + 4;
    __shared__ float Xs[256 * XP];
    __shared__ float Ws[KC * F];
    const int tid  = threadIdx.x;
    const int fgrp = tid & 7;
    const int ngrp = tid >> 3;
    const int f0   = fgrp * 8;
    const int nb   = blockIdx.x * 256;

    float acc[8][8];
#pragma unroll
    for (int i = 0; i < 8; i++)
#pragma unroll
        for (int j = 0; j < 8; j++) acc[i][j] = 0.0f;

    for (int kc = 0; kc < K; kc += KC) {
        if (kc) __syncthreads();
#pragma unroll
        for (int pass = 0; pass < 8; pass++) {
            int idx = tid + pass * 256;
            int r = idx >> 3, q = idx & 7;
            int gr = nb + r; if (gr >= N_NODES) gr = N_NODES - 1;
            float4 v = *(const float4*)&X[(size_t)gr * K + kc + q * 4];
            *(float4*)&Xs[r * XP + q * 4] = v;
        }
#pragma unroll
        for (int pass = 0; pass < 2; pass++) {
            int idx = tid + pass * 256;
            float4 v = *(const float4*)&W[(size_t)(kc + (idx >> 4)) * F + (idx & 15) * 4];
            *(float4*)&Ws[idx * 4] = v;
        }
        __syncthreads();
#pragma unroll
        for (int k = 0; k < KC; k += 4) {
            float4 wa[4], wb[4];
#pragma unroll
            for (int kk = 0; kk < 4; kk++) {
                wa[kk] = *(const float4*)&Ws[(k + kk) * F + f0];
                wb[kk] = *(const float4*)&Ws[(k + kk) * F + f0 + 4];
            }
#pragma unroll
            for (int i = 0; i < 8; i++) {
                float4 xv = *(const float4*)&Xs[(ngrp + 32 * i) * XP + k];
#pragma unroll
                for (int kk = 0; kk < 4; kk++) {
                    float xk = (kk == 0) ? xv.x : (kk == 1) ? xv.y : (kk == 2) ? xv.z : xv.w;
                    acc[i][0] = fmaf(xk, wa[kk].x, acc[i][0]);
                    acc[i][1] = fmaf(xk, wa[kk].y, acc[i][1]);
                    acc[i][2] = fmaf(xk, wa[kk].z, acc[i][2]);
                    acc[i][3] = fmaf(xk, wa[kk].w, acc[i][3]);
                    acc[i][4] = fmaf(xk, wb[kk].x, acc[i][4]);
                    acc[i][5] = fmaf(xk, wb[kk].y, acc[i][5]);
                    acc[i][6] = fmaf(xk, wb[kk].z, acc[i][6]);
                    acc[i][7] = fmaf(xk, wb[kk].w, acc[i][7]);
                }
            }
        }
    }
#pragma unroll
    for (int i = 0; i < 8; i++) {
        int gn = nb + ngrp + 32 * i;
        if (gn < N_NODES) {
            __hip_bfloat16 hb[8];
#pragma unroll
            for (int j = 0; j < 8; j++) hb[j] = __float2bfloat16(acc[i][j]);
            *(uint4*)&H[(size_t)gn * F + f0] = *(uint4*)hb;
        }
    }
}

// ---------------- GEMM (layers 2/3): H = X_bf16[N,64] @ W[64,64], bf16 out ----------------
template <int K>
__global__ __launch_bounds__(256) void k_gemm(const unsigned short* __restrict__ X,
                                              const float* __restrict__ W,
                                              __hip_bfloat16* __restrict__ H) {
    constexpr int KC = 32;
    constexpr int XP = KC + 4;
    __shared__ float Xs[256 * XP];
    __shared__ float Ws[KC * F];
    const int tid  = threadIdx.x;
    const int fgrp = tid & 7;
    const int ngrp = tid >> 3;
    const int f0   = fgrp * 8;
    const int nb   = blockIdx.x * 256;

    float acc[8][8];
#pragma unroll
    for (int i = 0; i < 8; i++)
#pragma unroll
        for (int j = 0; j < 8; j++) acc[i][j] = 0.0f;

    for (int kc = 0; kc < K; kc += KC) {
        if (kc) __syncthreads();
#pragma unroll
        for (int pass = 0; pass < 4; pass++) {
            int idx = tid + pass * 256;
            int r = idx >> 2, q = idx & 3;
            int gr = nb + r; if (gr >= N_NODES) gr = N_NODES - 1;
            uint4 v = *(const uint4*)&X[(size_t)gr * K + kc + q * 8];
            float* dp = &Xs[r * XP + q * 8];
            dp[0] = __uint_as_float(v.x << 16);
            dp[1] = __uint_as_float(v.x & 0xffff0000u);
            dp[2] = __uint_as_float(v.y << 16);
            dp[3] = __uint_as_float(v.y & 0xffff0000u);
            dp[4] = __uint_as_float(v.z << 16);
            dp[5] = __uint_as_float(v.z & 0xffff0000u);
            dp[6] = __uint_as_float(v.w << 16);
            dp[7] = __uint_as_float(v.w & 0xffff0000u);
        }
#pragma unroll
        for (int pass = 0; pass < 2; pass++) {
            int idx = tid + pass * 256;
            float4 v = *(const float4*)&W[(size_t)(kc + (idx >> 4)) * F + (idx & 15) * 4];
            *(float4*)&Ws[idx * 4] = v;
        }
        __syncthreads();
#pragma unroll
        for (int k = 0; k < KC; k += 4) {
            float4 wa[4], wb[4];
#pragma unroll
            for (int kk = 0; kk < 4; kk++) {
                wa[kk] = *(const float4*)&Ws[(k + kk) * F + f0];
                wb[kk] = *(const float4*)&Ws[(k + kk) * F + f0 + 4];
            }
#pragma unroll
            for (int i = 0; i < 8; i++) {
                float4 xv = *(const float4*)&Xs[(ngrp + 32 * i) * XP + k];
#pragma unroll
                for (int kk = 0; kk < 4; kk++) {
                    float xk = (kk == 0) ? xv.x : (kk == 1) ? xv.y : (kk == 2) ? xv.z : xv.w;
                    acc[i][0] = fmaf(xk, wa[kk].x, acc[i][0]);
                    acc[i][1] = fmaf(xk, wa[kk].y, acc[i][1]);
                    acc[i][2] = fmaf(xk, wa[kk].z, acc[i][2]);
                    acc[i][3] = fmaf(xk, wa[kk].w, acc[i][3]);
                    acc[i][4] = fmaf(xk, wb[kk].x, acc[i][4]);
                    acc[i][5] = fmaf(xk, wb[kk].y, acc[i][5]);
                    acc[i][6] = fmaf(xk, wb[kk].z, acc[i][6]);
                    acc[i][7] = fmaf(xk, wb[kk].w, acc[i][7]);
                }
            }
        }
    }
#pragma unroll
    for (int i = 0; i < 8; i++) {
        int gn = nb + ngrp + 32 * i;
        if (gn < N_NODES) {
            __hip_bfloat16 hb[8];
#pragma unroll
            for (int j = 0; j < 8; j++) hb[j] = __float2bfloat16(acc[i][j]);
            *(uint4*)&H[(size_t)gn * F + f0] = *(uint4*)hb;
        }
    }
}

// ---------------- aggregation: O = relu(b + dinv^2*H + sum_in c*H[src]) ----------------
// EIGHT nodes per wave (8 independent gather chains) + esec software pipeline.
// __launch_bounds__(256,2) caps VGPR at 256 so the allocator never spills the
// gather batch (r10 lesson: spill -> 474 MB scratch). Epilogue uses all 64
// lanes: lane group q writes node np+q (1 KB contiguous per wave).
__global__ __launch_bounds__(256, 2) void k_agg(const __hip_bfloat16* __restrict__ H,
                                                const int* __restrict__ row_off,
                                                const int2* __restrict__ esec,
                                                const float* __restrict__ dinv,
                                                const float* __restrict__ bias,
                                                __hip_bfloat16* __restrict__ O) {
    int wv   = threadIdx.x >> 6;
    int lane = threadIdx.x & 63;
    int np   = blockIdx.x * 32 + wv * 8;
    int q  = lane >> 3;
    int f8 = lane & 7;
    int r[9];
#pragma unroll
    for (int i = 0; i < 9; i++) r[i] = __builtin_amdgcn_readfirstlane(row_off[np + i]);
    const char* Hbase = (const char*)H;

    float a[8][8];
#pragma unroll
    for (int n = 0; n < 8; n++)
#pragma unroll
        for (int u = 0; u < 8; u++) a[n][u] = 0.0f;

    int ml = 0;
#pragma unroll
    for (int n = 0; n < 8; n++) { int l = r[n + 1] - r[n]; if (l > ml) ml = l; }
    int iters = (ml + 7) >> 3;

    int jb[8];
    int2 ev[8];
#pragma unroll
    for (int n = 0; n < 8; n++) {
        jb[n] = r[n] + q;
        ev[n] = esec[jb[n] < N_EDGES ? jb[n] : N_EDGES];
    }

    for (int it = 0; it < iters; it++) {
#pragma unroll
        for (int n = 0; n < 8; n++) {
            int nx = jb[n] + 8;
            int2 en = esec[nx < N_EDGES ? nx : N_EDGES];     // prefetch next window
            float c = (jb[n] < r[n + 1]) ? __int_as_float(ev[n].y) : 0.0f;
            uint4 h = *(const uint4*)(Hbase + (unsigned)ev[n].x + (f8 << 4));
            a[n][0] = fmaf(c, __uint_as_float(h.x << 16),         a[n][0]);
            a[n][1] = fmaf(c, __uint_as_float(h.x & 0xffff0000u), a[n][1]);
            a[n][2] = fmaf(c, __uint_as_float(h.y << 16),         a[n][2]);
            a[n][3] = fmaf(c, __uint_as_float(h.y & 0xffff0000u), a[n][3]);
            a[n][4] = fmaf(c, __uint_as_float(h.z << 16),         a[n][4]);
            a[n][5] = fmaf(c, __uint_as_float(h.z & 0xffff0000u), a[n][5]);
            a[n][6] = fmaf(c, __uint_as_float(h.w << 16),         a[n][6]);
            a[n][7] = fmaf(c, __uint_as_float(h.w & 0xffff0000u), a[n][7]);
            ev[n] = en;
            jb[n] = nx;
        }
    }
#pragma unroll
    for (int m = 8; m < 64; m <<= 1) {
#pragma unroll
        for (int n = 0; n < 8; n++)
#pragma unroll
            for (int u = 0; u < 8; u++) a[n][u] += __shfl_xor(a[n][u], m);
    }
    // lane group q owns node np+q
    int node = np + q;
    float av[8];
#pragma unroll
    for (int u = 0; u < 8; u++) {
        float t0 = (q & 1) ? a[1][u] : a[0][u];
        float t1 = (q & 1) ? a[3][u] : a[2][u];
        float t2 = (q & 1) ? a[5][u] : a[4][u];
        float t3 = (q & 1) ? a[7][u] : a[6][u];
        float s0 = (q & 2) ? t1 : t0;
        float s1 = (q & 2) ? t3 : t2;
        av[u] = (q & 4) ? s1 : s0;
    }
    float di = dinv[node];
    float di2 = di * di;
    uint4 hs = *(const uint4*)(Hbase + (size_t)node * 128 + (f8 << 4));
    float hv[8];
    hv[0] = __uint_as_float(hs.x << 16);
    hv[1] = __uint_as_float(hs.x & 0xffff0000u);
    hv[2] = __uint_as_float(hs.y << 16);
    hv[3] = __uint_as_float(hs.y & 0xffff0000u);
    hv[4] = __uint_as_float(hs.z << 16);
    hv[5] = __uint_as_float(hs.z & 0xffff0000u);
    hv[6] = __uint_as_float(hs.w << 16);
    hv[7] = __uint_as_float(hs.w & 0xffff0000u);
    const float4* bp = (const float4*)(bias + f8 * 8);
    float4 bv0 = bp[0], bv1 = bp[1];
    float rr[8];
    rr[0] = fmaxf(av[0] + bv0.x + di2 * hv[0], 0.0f);
    rr[1] = fmaxf(av[1] + bv0.y + di2 * hv[1], 0.0f);
    rr[2] = fmaxf(av[2] + bv0.z + di2 * hv[2], 0.0f);
    rr[3] = fmaxf(av[3] + bv0.w + di2 * hv[3], 0.0f);
    rr[4] = fmaxf(av[4] + bv1.x + di2 * hv[4], 0.0f);
    rr[5] = fmaxf(av[5] + bv1.y + di2 * hv[5], 0.0f);
    rr[6] = fmaxf(av[6] + bv1.z + di2 * hv[6], 0.0f);
    rr[7] = fmaxf(av[7] + bv1.w + di2 * hv[7], 0.0f);
    __hip_bfloat16 hb[8];
#pragma unroll
    for (int u = 0; u < 8; u++) hb[u] = __float2bfloat16(rr[u]);
    *(uint4*)&O[(size_t)node * F + f8 * 8] = *(uint4*)hb;
}

// ---------------- fused mean-pool + final linear (bf16 input) ----------------
__global__ __launch_bounds__(256) void k_pool_linear(const __hip_bfloat16* __restrict__ H,
                                                     const int* __restrict__ gstart,
                                                     const float* __restrict__ Wl,
                                                     const float* __restrict__ bl,
                                                     float* __restrict__ out) {
    int g = blockIdx.x;
    int beg = gstart[g], end = gstart[g + 1];
    int lane = threadIdx.x & 63, wv = threadIdx.x >> 6;
    float acc = 0.0f;
    for (int r = beg + wv; r < end; r += 4)
        acc += __bfloat162float(H[(size_t)r * F + lane]);
    __shared__ float s[4][F];
    s[wv][lane] = acc;
    __syncthreads();
    if (wv == 0) {
        float tot = s[0][lane] + s[1][lane] + s[2][lane] + s[3][lane];
        float cntf = (float)(end - beg);
        float p = tot / fmaxf(cntf, 1.0f);
        for (int c = 0; c < 10; c++) {
            float v = p * Wl[lane * 10 + c];
            for (int off = 32; off; off >>= 1) v += __shfl_down(v, off);
            if (lane == 0) out[g * 10 + c] = v + bl[c];
        }
    }
}

// ---------------- launch ----------------

extern "C" void kernel_launch(void* const* d_in, const int* in_sizes, int n_in,
                              void* d_out, int out_size, void* d_ws, size_t ws_size,
                              hipStream_t stream) {
    const float* x    = (const float*)d_in[0];
    const int*   ei   = (const int*)d_in[1];
    const float* ea   = (const float*)d_in[2];
    const int*   bat  = (const int*)d_in[3];
    const float* W1   = (const float*)d_in[4];
    const float* b1   = (const float*)d_in[5];
    const float* W2   = (const float*)d_in[6];
    const float* b2   = (const float*)d_in[7];
    const float* W3   = (const float*)d_in[8];
    const float* b3   = (const float*)d_in[9];
    const float* Wl   = (const float*)d_in[10];
    const float* bl   = (const float*)d_in[11];
    float* out = (float*)d_out;

    const int* src = ei;
    const int* dst = ei + N_EDGES;

    char* ws = (char*)d_ws;
    size_t off = 0;
    auto carve = [&](size_t bytes) {
        void* p = ws + off;
        off += (bytes + 255) & ~(size_t)255;
        return p;
    };
    float*          dinv    = (float*)carve(N_NODES * 4);
    int*            row_off = (int*)  carve((N_NODES + 1) * 4);
    int2*           esec    = (int2*) carve(((size_t)N_EDGES + 32) * 8);        // 12.8 MB
    __hip_bfloat16* hbuf    = (__hip_bfloat16*)carve((size_t)N_NODES * F * 2);  // 12.8 MB
    __hip_bfloat16* obuf    = (__hip_bfloat16*)carve((size_t)N_NODES * F * 2);  // 12.8 MB
    long long*      part    = (long long*)carve((size_t)N_EDGES * 8);           // 12.8 MB
    int*            hist    = (int*)  carve((size_t)NCHUNK * NBUCK * 4);        // 1.22 MB
    int*            btot    = (int*)  carve((NBUCK + 8) * 4);
    int*            base    = (int*)  carve((NBUCK + 8) * 4);
    int*            gstart  = (int*)  carve((N_GRAPHS + 1) * 4);
    (void)ws_size; (void)in_sizes; (void)n_in; (void)out_size;

    k_hist     <<<NCHUNK + 1, 1024, 0, stream>>>(dst, hist, bat, gstart);
    k_colscan  <<<NBUCK,      512,  0, stream>>>(hist, btot);
    k_bscan    <<<1,          256,  0, stream>>>(btot, base);
    k_partition<<<NCHUNK,     1024, 0, stream>>>(src, dst, ea, hist, base, part);
    k_deg      <<<NBUCK,      512,  0, stream>>>(part, base, dinv, row_off);
    k_scat     <<<NBUCK,      512,  0, stream>>>(part, base, dinv, row_off, esec);

    k_gemm1<<<GB, 256, 0, stream>>>(x, W1, hbuf);
    k_agg<<<N_NODES / 32, 256, 0, stream>>>(hbuf, row_off, esec, dinv, b1, obuf);
    k_gemm<64><<<GB, 256, 0, stream>>>((const unsigned short*)obuf, W2, hbuf);
    k_agg<<<N_NODES / 32, 256, 0, stream>>>(hbuf, row_off, esec, dinv, b2, obuf);
    k_gemm<64><<<GB, 256, 0, stream>>>((const unsigned short*)obuf, W3, hbuf);
    k_agg<<<N_NODES / 32, 256, 0, stream>>>(hbuf, row_off, esec, dinv, b3, obuf);

    k_pool_linear<<<N_GRAPHS, 256, 0, stream>>>(obuf, gstart, Wl, bl, out);
}